// Round 1
// 121.855 us; speedup vs baseline: 1.0526x; 1.0526x over previous
//
#include <hip/hip_runtime.h>
#include <hip/hip_bf16.h>
#include <math.h>

#define B 4
#define N 2048
#define FIN 256
#define H 4
#define FO 64
#define M (B*N)        // 8192 rows
#define HF (H*FO)      // 256 cols

typedef __attribute__((ext_vector_type(8))) short short8;    // 8x16b (4 VGPRs)
typedef __attribute__((ext_vector_type(8))) _Float16 half8;  // MFMA f16 A/B
typedef __attribute__((ext_vector_type(2))) _Float16 half2v; // v_pk_* pair
typedef __attribute__((ext_vector_type(4))) float float4v;   // MFMA C/D
typedef __attribute__((ext_vector_type(4))) int int4v;

#if __has_builtin(__builtin_amdgcn_exp2f)
#define EXP2(x) __builtin_amdgcn_exp2f(x)
#else
#define EXP2(x) exp2f(x)
#endif

// split x into hi (truncated bf16) + lo (truncated bf16 of remainder), packed pairs
static __device__ __forceinline__ void split_pair(float x0, float x1,
                                                  unsigned int& hi, unsigned int& lo) {
  unsigned int u0 = __builtin_bit_cast(unsigned int, x0);
  unsigned int u1 = __builtin_bit_cast(unsigned int, x1);
  hi = (u0 >> 16) | (u1 & 0xffff0000u);
  float h0 = __builtin_bit_cast(float, u0 & 0xffff0000u);
  float h1 = __builtin_bit_cast(float, u1 & 0xffff0000u);
  unsigned int l0 = __builtin_bit_cast(unsigned int, x0 - h0);
  unsigned int l1 = __builtin_bit_cast(unsigned int, x1 - h1);
  lo = (l0 >> 16) | (l1 & 0xffff0000u);
}

// monotone float<->uint encoding for atomicMax
static __device__ __forceinline__ unsigned int fenc(float f) {
  unsigned int b = __builtin_bit_cast(unsigned int, f);
  return (b & 0x80000000u) ? ~b : (b | 0x80000000u);
}
static __device__ __forceinline__ float fdec(unsigned int e) {
  unsigned int b = (e & 0x80000000u) ? (e & 0x7fffffffu) : ~e;
  return __builtin_bit_cast(float, b);
}

// 1-bit sign-extended extract: 0 or 0xFFFFFFFF (v_bfe_i32)
static __device__ __forceinline__ unsigned int bit_sext(unsigned int v, int k) {
#if __has_builtin(__builtin_amdgcn_sbfe)
  return (unsigned int)__builtin_amdgcn_sbfe((int)v, k, 1);
#else
  return (unsigned int)(((int)(v << (31 - k))) >> 31);
#endif
}
// pair mask: lo16 = bit(2p) replicated, hi16 = bit(2p+1) replicated (2 bfe + 1 perm)
static __device__ __forceinline__ unsigned int pm2(unsigned int mk, int p) {
  return __builtin_amdgcn_perm(bit_sext(mk, 2 * p + 1), bit_sext(mk, 2 * p), 0x07060302u);
}
// two f32 -> packed f16 pair (v_cvt_pkrtz_f16_f32, 1 op)
static __device__ __forceinline__ unsigned int f16pk(float a, float b) {
  auto h = __builtin_amdgcn_cvt_pkrtz(a, b);
  return __builtin_bit_cast(unsigned int, h);
}

// ---- Kernel 1: [0..15] W -> Wf (fragment-ordered bf16 hi/lo pair)
//      [16..527] X -> Xf, ONE (row-tile, k-tile) per block (r15: was 4 serialized
//      k-tiles in 128 blocks on a 256-CU chip; 512 blocks removes the barrier loop)
__global__ __launch_bounds__(256) void prep_wx(const float* __restrict__ Wsrc,
                                               const float* __restrict__ X,
                                               unsigned short* __restrict__ Wf_hi,
                                               unsigned short* __restrict__ Wf_lo,
                                               unsigned short* __restrict__ Xf_hi,
                                               unsigned short* __restrict__ Xf_lo,
                                               unsigned int* __restrict__ DmaxEnc) {
  const int blk = blockIdx.x;
  const int t = threadIdx.x;
  __shared__ float lds[64][65];
  if (blk < 16) {
    if (blk == 0 && t < 16) DmaxEnc[t] = 0u;
    const int k0 = (blk >> 2) * 64;
    const int h  = blk & 3;
    const int n0 = h * 64;
    const int c4 = (t & 15) * 4;
    #pragma unroll
    for (int rep = 0; rep < 4; ++rep) {
      const int kl = (t >> 4) + 16 * rep;
      const float4 v = *(const float4*)(Wsrc + (size_t)(k0 + kl) * HF + n0 + c4);
      lds[kl][c4 + 0] = v.x; lds[kl][c4 + 1] = v.y;
      lds[kl][c4 + 2] = v.z; lds[kl][c4 + 3] = v.w;
    }
    __syncthreads();
    #pragma unroll
    for (int rep = 0; rep < 2; ++rep) {
      const int s   = t + rep * 256;
      const int kcl = s >> 8;
      const int tt  = (s >> 6) & 3;
      const int ln  = s & 63;
      const int fL  = tt * 16 + (ln & 15);
      const int kb  = kcl * 32 + (ln >> 4) * 8;
      unsigned int hv[4], lv[4];
      #pragma unroll
      for (int p = 0; p < 4; ++p)
        split_pair(lds[kb + 2 * p][fL], lds[kb + 2 * p + 1][fL], hv[p], lv[p]);
      const size_t off = ((((size_t)h * 8 + (k0 >> 5) + kcl) * 4 + tt) << 9) + ln * 8;
      *(uint4*)(Wf_hi + off) = make_uint4(hv[0], hv[1], hv[2], hv[3]);
      *(uint4*)(Wf_lo + off) = make_uint4(lv[0], lv[1], lv[2], lv[3]);
    }
    return;
  }
  // ---- X prep: one (xblk, ktile) per block, A-fragment order ----
  const int xb2   = blk - 16;          // 0..511
  const int xblk  = xb2 >> 2;          // 0..127 (row tile of 64)
  const int ktile = xb2 & 3;           // 0..3  (k tile of 64)
  const int mrow0 = xblk * 64;
  const int k0 = ktile * 64;
  const int c4 = (t & 15) * 4;
  #pragma unroll
  for (int rep = 0; rep < 4; ++rep) {
    const int rl = (t >> 4) + 16 * rep;
    const float4 v = *(const float4*)(X + (size_t)(mrow0 + rl) * FIN + k0 + c4);
    lds[rl][c4 + 0] = v.x; lds[rl][c4 + 1] = v.y;
    lds[rl][c4 + 2] = v.z; lds[rl][c4 + 3] = v.w;
  }
  __syncthreads();
  #pragma unroll
  for (int rep = 0; rep < 2; ++rep) {
    const int s   = t + rep * 256;
    const int mt  = s >> 7;
    const int kcl = (s >> 6) & 1;
    const int ln  = s & 63;
    const int mrl = mt * 16 + (ln & 15);
    const int kb  = kcl * 32 + (ln >> 4) * 8;
    unsigned int hv[4], lv[4];
    #pragma unroll
    for (int p = 0; p < 4; ++p)
      split_pair(lds[mrl][kb + 2 * p], lds[mrl][kb + 2 * p + 1], hv[p], lv[p]);
    const size_t off = (((size_t)(xblk * 4 + mt) * 8 + (ktile * 2 + kcl)) << 9) + ln * 8;
    *(uint4*)(Xf_hi + off) = make_uint4(hv[0], hv[1], hv[2], hv[3]);
    *(uint4*)(Xf_lo + off) = make_uint4(lv[0], lv[1], lv[2], lv[3]);
  }
}

// ---- Kernel 2: [0..511] fused h=x@W (bf16x2 MFMA) + epilogue
//      [512..2559] adj rows -> bitmasks (overlaps with gemm blocks)
//      r15: Hf and the E-planes are now f16 (feeds the f16 aggregation MFMA;
//      11-bit mantissa — MORE precise than the previous bf16 path)
__global__ __launch_bounds__(256) void gemm_fused(const unsigned short* __restrict__ Xf_hi,
                                                  const unsigned short* __restrict__ Xf_lo,
                                                  const unsigned short* __restrict__ Wf_hi,
                                                  const unsigned short* __restrict__ Wf_lo,
                                                  const float* __restrict__ adj,
                                                  const float* __restrict__ a_src,
                                                  const float* __restrict__ a_dst,
                                                  float* __restrict__ Srcv,
                                                  unsigned short* __restrict__ E1h,
                                                  unsigned short* __restrict__ E2h,
                                                  unsigned int* __restrict__ DmaxEnc,
                                                  unsigned long long* __restrict__ packed,
                                                  unsigned short* __restrict__ Hf) {
  if (blockIdx.x >= 512) {
    const int row = blockIdx.x - 512;
    const int pw = threadIdx.x >> 6, pl = threadIdx.x & 63;
    const float* ar = adj + (size_t)row * N;
    for (int c = pw; c < N / 64; c += 4) {
      unsigned long long m = __ballot(ar[c * 64 + pl] != 0.f);
      if (pl == 0) packed[(size_t)row * (N / 64) + c] = m;
    }
    return;
  }
  __shared__ unsigned short sh[64][72];
  __shared__ float smax[4];
  const int xcd  = blockIdx.x & 7;
  const int slot = blockIdx.x >> 3;
  const int mb = xcd * 16 + (slot >> 2);
  const int h  = slot & 3;
  const int w = threadIdx.x >> 6, lane = threadIdx.x & 63;
  const int fl = lane & 15, quad = lane >> 4;
  const float L2E = 1.4426950408889634f;

  const float4v zero = {0.f, 0.f, 0.f, 0.f};
  float4v acc[4] = {zero, zero, zero, zero};

  const size_t abase = (((size_t)(mb * 4 + w) * 8) << 9) + lane * 8;
  #pragma unroll
  for (int kc = 0; kc < 8; ++kc) {
    const short8 Ahi = *(const short8*)(Xf_hi + abase + ((size_t)kc << 9));
    const short8 Alo = *(const short8*)(Xf_lo + abase + ((size_t)kc << 9));
    #pragma unroll
    for (int t = 0; t < 4; ++t) {
      const size_t woff = ((((size_t)h * 8 + kc) * 4 + t) << 9) + lane * 8;
      const short8 Bhi = *(const short8*)(Wf_hi + woff);
      const short8 Blo = *(const short8*)(Wf_lo + woff);
      acc[t] = __builtin_amdgcn_mfma_f32_16x16x32_bf16(Ahi, Bhi, acc[t], 0, 0, 0);
      acc[t] = __builtin_amdgcn_mfma_f32_16x16x32_bf16(Alo, Bhi, acc[t], 0, 0, 0);
      acc[t] = __builtin_amdgcn_mfma_f32_16x16x32_bf16(Ahi, Blo, acc[t], 0, 0, 0);
    }
  }

  // ---- Src dot, E-planes (f16), wave max of d ----
  const int bb  = (mb * 64) >> 11;
  const int n0w = (mb * 64) & (N - 1);
  const int bh  = bb * H + h;
  float as[4], ad[4];
  #pragma unroll
  for (int t = 0; t < 4; ++t) {
    as[t] = a_src[h * FO + t * 16 + fl];
    ad[t] = a_dst[h * FO + t * 16 + fl];
  }
  float wmax = -INFINITY;
  #pragma unroll
  for (int reg = 0; reg < 4; ++reg) {
    float sv = 0.f, dv = 0.f;
    #pragma unroll
    for (int t = 0; t < 4; ++t) {
      sv = fmaf(acc[t][reg], as[t], sv);
      dv = fmaf(acc[t][reg], ad[t], dv);
    }
    #pragma unroll
    for (int off = 1; off <= 8; off <<= 1) {
      sv += __shfl_xor(sv, off, 64);
      dv += __shfl_xor(dv, off, 64);
    }
    wmax = fmaxf(wmax, dv);
    if (fl == 0) {
      const int node = n0w + w * 16 + quad * 4 + reg;
      Srcv[(bh << 11) + node] = sv;
      const unsigned int eu = f16pk(EXP2(dv * L2E),            // exp(d)
                                    EXP2(dv * (0.2f * L2E)));  // exp(0.2 d)
      E1h[(bh << 11) + node] = (unsigned short)(eu & 0xffffu);
      E2h[(bh << 11) + node] = (unsigned short)(eu >> 16);
    }
  }
  wmax = fmaxf(wmax, __shfl_xor(wmax, 16, 64));
  wmax = fmaxf(wmax, __shfl_xor(wmax, 32, 64));
  if (lane == 0) smax[w] = wmax;

  // ---- stage f16 tile: sh[f][node] ----
  #pragma unroll
  for (int t = 0; t < 4; ++t) {
    const int nl = w * 16 + quad * 4;
    *(unsigned int*)&sh[t * 16 + fl][nl]     = f16pk(acc[t][0], acc[t][1]);
    *(unsigned int*)&sh[t * 16 + fl][nl + 2] = f16pk(acc[t][2], acc[t][3]);
  }
  __syncthreads();
  if (threadIdx.x == 0) {
    const float bmax = fmaxf(fmaxf(smax[0], smax[1]), fmaxf(smax[2], smax[3]));
    atomicMax(DmaxEnc + bh, fenc(bmax));
  }
  // ---- fragment-ordered Hf write ----
  const int jc0 = n0w >> 5;
  #pragma unroll
  for (int rep = 0; rep < 2; ++rep) {
    const int s = (int)threadIdx.x + rep * 256;
    const int jcl = s >> 8;
    const int tt  = (s >> 6) & 3;
    const int ln  = s & 63;
    const int f    = tt * 16 + (ln & 15);
    const int node = jcl * 32 + (ln >> 4) * 8;
    unsigned short* dsth = Hf + (((size_t)bh * 64 + jc0 + jcl) * 4 + tt) * 512 + ln * 8;
    *(uint4*)dsth = *(const uint4*)&sh[f][node];
  }
}

// ---- Kernel 3: MFMA flash aggregation (r15: packed-f16 weight pipeline)
// Grid: B*(N/32)=256 blocks, 512 thr (8 waves: 4 heads x 2 j-halves).
// Per-edge weight = exp(lrelu(z)-m) = max(c1*E1, c2*E2) (exp monotone) — branchless,
// computed 2-at-a-time with v_pk_mul_f16 / v_pk_max_f16; adjacency applied as a
// 16-bit AND mask (2x v_bfe_i32 + v_perm per pair). Weights come out pre-packed
// for the f16 MFMA A-operand (no v_perm pack step). ~68 VALU/it vs ~130 before.
// NOTE: plain __launch_bounds__ — min-waves bound splits unified VGPR/AGPR
// file and spills (r9: 172MB scratch traffic). Never force it.
__global__ __launch_bounds__(512) void gat_mfma(const unsigned char* __restrict__ pb,
                                                const float* __restrict__ Src,
                                                const unsigned short* __restrict__ E1h,
                                                const unsigned short* __restrict__ E2h,
                                                const unsigned int* __restrict__ DmaxEnc,
                                                const unsigned short* __restrict__ Hf,
                                                float* __restrict__ out) {
  const int xcd  = blockIdx.x & 7;
  const int slot = blockIdx.x >> 3;          // 0..31
  const int b    = xcd >> 1;
  const int i0   = ((xcd & 1) * 32 + slot) * 32;
  const int w    = threadIdx.x >> 6;         // 0..7
  const int lane = threadIdx.x & 63;
  const int h    = w & 3;
  const int jh   = w >> 2;                   // j half
  const int bh   = b * H + h;
  const int fl   = lane & 15;
  const int kk   = (lane >> 4) * 8;
  const float L2E = 1.4426950408889634f;

  const int row0 = i0 + fl;
  const int row1 = i0 + 16 + fl;
  const float dmx = fdec(DmaxEnc[bh]);
  const float s0 = Src[(bh << 11) + row0];
  const float s1 = Src[(bh << 11) + row1];
  const float u0 = s0 + dmx, m0 = fmaxf(u0, 0.2f * u0);
  const float u1 = s1 + dmx, m1 = fmaxf(u1, 0.2f * u1);
  const float c1a = EXP2((s0 - m0) * L2E), c2a = EXP2((0.2f * s0 - m0) * L2E);
  const float c1b = EXP2((s1 - m1) * L2E), c2b = EXP2((0.2f * s1 - m1) * L2E);
  // f16 row constants (all <= ~e^3.5, far inside f16 range)
  const half2v c1a2 = {(_Float16)c1a, (_Float16)c1a};
  const half2v c2a2 = {(_Float16)c2a, (_Float16)c2a};
  const half2v c1b2 = {(_Float16)c1b, (_Float16)c1b};
  const half2v c2b2 = {(_Float16)c2b, (_Float16)c2b};
  const unsigned char* pb0 = pb + (size_t)row0 * (N / 8);
  const unsigned char* pb1 = pb + (size_t)row1 * (N / 8);
  const unsigned short* hfb = Hf + (size_t)bh * 64 * 2048 + lane * 8;
  const unsigned short* e1b = E1h + (bh << 11);
  const unsigned short* e2b = E2h + (bh << 11);

  half8 ones;
  #pragma unroll
  for (int jj = 0; jj < 8; ++jj) ones[jj] = (_Float16)1.0f;

  const float4v zero = {0.f, 0.f, 0.f, 0.f};
  float4v acc[2][4];
  float4v accL[2];
  #pragma unroll
  for (int rt = 0; rt < 2; ++rt) {
    accL[rt] = zero;
    #pragma unroll
    for (int t = 0; t < 4; ++t) acc[rt][t] = zero;
  }

  const int jbeg = jh * (N / 2);
  // ---- prefetch chunk 0 ----
  short8 nb0, nb1, nb2, nb3;
  uint4 nE1, nE2;
  unsigned int nm0, nm1;
  {
    const unsigned short* hc = hfb + (size_t)(jbeg >> 5) * 2048;
    nb0 = *(const short8*)(hc + 0 * 512);
    nb1 = *(const short8*)(hc + 1 * 512);
    nb2 = *(const short8*)(hc + 2 * 512);
    nb3 = *(const short8*)(hc + 3 * 512);
    nE1 = *(const uint4*)(e1b + jbeg + kk);
    nE2 = *(const uint4*)(e2b + jbeg + kk);
    nm0 = pb0[(jbeg + kk) >> 3];
    nm1 = pb1[(jbeg + kk) >> 3];
  }

  for (int it = 0; it < 32; ++it) {
    const short8 b0 = nb0, b1 = nb1, b2 = nb2, b3 = nb3;
    const uint4 E1q = nE1, E2q = nE2;
    const unsigned int mk0 = nm0, mk1 = nm1;
    if (it < 31) {
      const int jn = jbeg + (it + 1) * 32;
      const unsigned short* hc = hfb + (size_t)(jn >> 5) * 2048;
      nb0 = *(const short8*)(hc + 0 * 512);
      nb1 = *(const short8*)(hc + 1 * 512);
      nb2 = *(const short8*)(hc + 2 * 512);
      nb3 = *(const short8*)(hc + 3 * 512);
      nE1 = *(const uint4*)(e1b + jn + kk);
      nE2 = *(const uint4*)(e2b + jn + kk);
      nm0 = pb0[(jn + kk) >> 3];
      nm1 = pb1[(jn + kk) >> 3];
    }
    const unsigned int e1w[4] = {E1q.x, E1q.y, E1q.z, E1q.w};
    const unsigned int e2w[4] = {E2q.x, E2q.y, E2q.z, E2q.w};
    int p0i[4], p1i[4];
    #pragma unroll
    for (int p = 0; p < 4; ++p) {
      const half2v e1 = __builtin_bit_cast(half2v, e1w[p]);
      const half2v e2 = __builtin_bit_cast(half2v, e2w[p]);
      const half2v wa = __builtin_elementwise_max(c1a2 * e1, c2a2 * e2);
      const half2v wb = __builtin_elementwise_max(c1b2 * e1, c2b2 * e2);
      p0i[p] = (int)(__builtin_bit_cast(unsigned int, wa) & pm2(mk0, p));
      p1i[p] = (int)(__builtin_bit_cast(unsigned int, wb) & pm2(mk1, p));
    }
    const half8 p0 = __builtin_bit_cast(half8, (int4v){p0i[0], p0i[1], p0i[2], p0i[3]});
    const half8 p1 = __builtin_bit_cast(half8, (int4v){p1i[0], p1i[1], p1i[2], p1i[3]});
    const half8 hb0 = __builtin_bit_cast(half8, b0);
    const half8 hb1 = __builtin_bit_cast(half8, b1);
    const half8 hb2 = __builtin_bit_cast(half8, b2);
    const half8 hb3 = __builtin_bit_cast(half8, b3);
    acc[0][0] = __builtin_amdgcn_mfma_f32_16x16x32_f16(p0, hb0, acc[0][0], 0, 0, 0);
    acc[0][1] = __builtin_amdgcn_mfma_f32_16x16x32_f16(p0, hb1, acc[0][1], 0, 0, 0);
    acc[0][2] = __builtin_amdgcn_mfma_f32_16x16x32_f16(p0, hb2, acc[0][2], 0, 0, 0);
    acc[0][3] = __builtin_amdgcn_mfma_f32_16x16x32_f16(p0, hb3, acc[0][3], 0, 0, 0);
    accL[0]   = __builtin_amdgcn_mfma_f32_16x16x32_f16(p0, ones, accL[0], 0, 0, 0);
    acc[1][0] = __builtin_amdgcn_mfma_f32_16x16x32_f16(p1, hb0, acc[1][0], 0, 0, 0);
    acc[1][1] = __builtin_amdgcn_mfma_f32_16x16x32_f16(p1, hb1, acc[1][1], 0, 0, 0);
    acc[1][2] = __builtin_amdgcn_mfma_f32_16x16x32_f16(p1, hb2, acc[1][2], 0, 0, 0);
    acc[1][3] = __builtin_amdgcn_mfma_f32_16x16x32_f16(p1, hb3, acc[1][3], 0, 0, 0);
    accL[1]   = __builtin_amdgcn_mfma_f32_16x16x32_f16(p1, ones, accL[1], 0, 0, 0);
  }

  // ---- combine the 2 j-halves: jh1 -> jh0 ----
  __shared__ float4v parts[4][64][11];   // 44 KiB
  if (jh == 1) {
    #pragma unroll
    for (int rt = 0; rt < 2; ++rt) {
      #pragma unroll
      for (int t = 0; t < 4; ++t) parts[h][lane][rt * 5 + t] = acc[rt][t];
      parts[h][lane][rt * 5 + 4] = accL[rt];
    }
  }
  __syncthreads();
  if (jh == 0) {
    #pragma unroll
    for (int rt = 0; rt < 2; ++rt) {
      #pragma unroll
      for (int t = 0; t < 4; ++t) acc[rt][t] += parts[h][lane][rt * 5 + t];
      accL[rt] += parts[h][lane][rt * 5 + 4];
    }
    const int quad = lane >> 4;
    #pragma unroll
    for (int rt = 0; rt < 2; ++rt) {
      #pragma unroll
      for (int reg = 0; reg < 4; ++reg) {
        const int r = i0 + rt * 16 + quad * 4 + reg;
        const float invl = 1.f / accL[rt][reg];
        float* op = out + ((size_t)(b * N) + r) * HF + h * FO + fl;
        #pragma unroll
        for (int t = 0; t < 4; ++t) op[t * 16] = acc[rt][t][reg] * invl;
      }
    }
  }
}

extern "C" void kernel_launch(void* const* d_in, const int* in_sizes, int n_in,
                              void* d_out, int out_size, void* d_ws, size_t ws_size,
                              hipStream_t stream) {
  const float* x     = (const float*)d_in[0];
  const float* adj   = (const float*)d_in[1];
  const float* W     = (const float*)d_in[2];
  const float* a_src = (const float*)d_in[3];
  const float* a_dst = (const float*)d_in[4];
  float* out = (float*)d_out;

  char* p = (char*)d_ws;
  float* Srcv = (float*)p;                  p += (size_t)B * H * N * 4;   // 128 KiB
  unsigned short* E1h = (unsigned short*)p; p += (size_t)B * H * N * 2;   // 64 KiB
  unsigned short* E2h = (unsigned short*)p; p += (size_t)B * H * N * 2;   // 64 KiB
  unsigned int* DmaxEnc = (unsigned int*)p; p += 256;
  unsigned short* Wfh = (unsigned short*)p; p += (size_t)HF * FIN * 2;    // 128 KiB
  unsigned short* Wfl = (unsigned short*)p; p += (size_t)HF * FIN * 2;    // 128 KiB
  unsigned short* Xfh = (unsigned short*)p; p += (size_t)M * FIN * 2;     // 4 MiB
  unsigned short* Xfl = (unsigned short*)p; p += (size_t)M * FIN * 2;     // 4 MiB
  unsigned short* Hf  = (unsigned short*)p; p += (size_t)M * HF * 2;      // 4 MiB
  unsigned long long* packed = (unsigned long long*)p;                    // 512 KiB

  prep_wx<<<dim3(528), dim3(256), 0, stream>>>(W, x, Wfh, Wfl, Xfh, Xfl, DmaxEnc);
  gemm_fused<<<dim3(512 + N), dim3(256), 0, stream>>>(Xfh, Xfl, Wfh, Wfl, adj,
                                                      a_src, a_dst,
                                                      Srcv, E1h, E2h, DmaxEnc,
                                                      packed, Hf);
  gat_mfma<<<dim3(B * (N / 32)), dim3(512), 0, stream>>>((const unsigned char*)packed,
                                                         Srcv, E1h, E2h, DmaxEnc, Hf, out);
}

// Round 2
// 121.633 us; speedup vs baseline: 1.0545x; 1.0018x over previous
//
#include <hip/hip_runtime.h>
#include <hip/hip_bf16.h>
#include <math.h>

#define B 4
#define N 2048
#define FIN 256
#define H 4
#define FO 64
#define M (B*N)        // 8192 rows
#define HF (H*FO)      // 256 cols

typedef __attribute__((ext_vector_type(8))) short short8;    // 8x16b (4 VGPRs)
typedef __attribute__((ext_vector_type(8))) _Float16 half8;  // MFMA f16 A/B
typedef __attribute__((ext_vector_type(2))) _Float16 half2v; // v_pk_* pair
typedef __attribute__((ext_vector_type(4))) float float4v;   // MFMA C/D
typedef __attribute__((ext_vector_type(4))) int int4v;

#if __has_builtin(__builtin_amdgcn_exp2f)
#define EXP2(x) __builtin_amdgcn_exp2f(x)
#else
#define EXP2(x) exp2f(x)
#endif

// split x into hi (truncated bf16) + lo (truncated bf16 of remainder), packed pairs
static __device__ __forceinline__ void split_pair(float x0, float x1,
                                                  unsigned int& hi, unsigned int& lo) {
  unsigned int u0 = __builtin_bit_cast(unsigned int, x0);
  unsigned int u1 = __builtin_bit_cast(unsigned int, x1);
  hi = (u0 >> 16) | (u1 & 0xffff0000u);
  float h0 = __builtin_bit_cast(float, u0 & 0xffff0000u);
  float h1 = __builtin_bit_cast(float, u1 & 0xffff0000u);
  unsigned int l0 = __builtin_bit_cast(unsigned int, x0 - h0);
  unsigned int l1 = __builtin_bit_cast(unsigned int, x1 - h1);
  lo = (l0 >> 16) | (l1 & 0xffff0000u);
}

// monotone float<->uint encoding for atomicMax
static __device__ __forceinline__ unsigned int fenc(float f) {
  unsigned int b = __builtin_bit_cast(unsigned int, f);
  return (b & 0x80000000u) ? ~b : (b | 0x80000000u);
}
static __device__ __forceinline__ float fdec(unsigned int e) {
  unsigned int b = (e & 0x80000000u) ? (e & 0x7fffffffu) : ~e;
  return __builtin_bit_cast(float, b);
}

// two f32 -> packed f16 pair (v_cvt_pkrtz_f16_f32, 1 op)
static __device__ __forceinline__ unsigned int f16pk(float a, float b) {
  auto h = __builtin_amdgcn_cvt_pkrtz(a, b);
  return __builtin_bit_cast(unsigned int, h);
}

// gat double-buffer chunk (static-named A/B ping-pong; rule #20: no runtime idx)
struct Chunk {
  short8 b0, b1, b2, b3;   // Hf: 32 j x 64 f
  uint4 e1, e2;            // E1/E2 planes, 8 f16 each per lane
  uint4 m0, m1;            // expanded 16-bit adjacency masks, rows 0/1
};

// ---- Kernel 1: [0..15] W -> Wf (fragment-ordered bf16 hi/lo pair)
//      [16..527] X -> Xf, ONE (row-tile, k-tile) per block
__global__ __launch_bounds__(256) void prep_wx(const float* __restrict__ Wsrc,
                                               const float* __restrict__ X,
                                               unsigned short* __restrict__ Wf_hi,
                                               unsigned short* __restrict__ Wf_lo,
                                               unsigned short* __restrict__ Xf_hi,
                                               unsigned short* __restrict__ Xf_lo,
                                               unsigned int* __restrict__ DmaxEnc) {
  const int blk = blockIdx.x;
  const int t = threadIdx.x;
  __shared__ float lds[64][65];
  if (blk < 16) {
    if (blk == 0 && t < 16) DmaxEnc[t] = 0u;
    const int k0 = (blk >> 2) * 64;
    const int h  = blk & 3;
    const int n0 = h * 64;
    const int c4 = (t & 15) * 4;
    #pragma unroll
    for (int rep = 0; rep < 4; ++rep) {
      const int kl = (t >> 4) + 16 * rep;
      const float4 v = *(const float4*)(Wsrc + (size_t)(k0 + kl) * HF + n0 + c4);
      lds[kl][c4 + 0] = v.x; lds[kl][c4 + 1] = v.y;
      lds[kl][c4 + 2] = v.z; lds[kl][c4 + 3] = v.w;
    }
    __syncthreads();
    #pragma unroll
    for (int rep = 0; rep < 2; ++rep) {
      const int s   = t + rep * 256;
      const int kcl = s >> 8;
      const int tt  = (s >> 6) & 3;
      const int ln  = s & 63;
      const int fL  = tt * 16 + (ln & 15);
      const int kb  = kcl * 32 + (ln >> 4) * 8;
      unsigned int hv[4], lv[4];
      #pragma unroll
      for (int p = 0; p < 4; ++p)
        split_pair(lds[kb + 2 * p][fL], lds[kb + 2 * p + 1][fL], hv[p], lv[p]);
      const size_t off = ((((size_t)h * 8 + (k0 >> 5) + kcl) * 4 + tt) << 9) + ln * 8;
      *(uint4*)(Wf_hi + off) = make_uint4(hv[0], hv[1], hv[2], hv[3]);
      *(uint4*)(Wf_lo + off) = make_uint4(lv[0], lv[1], lv[2], lv[3]);
    }
    return;
  }
  // ---- X prep: one (xblk, ktile) per block, A-fragment order ----
  const int xb2   = blk - 16;          // 0..511
  const int xblk  = xb2 >> 2;          // 0..127 (row tile of 64)
  const int ktile = xb2 & 3;           // 0..3  (k tile of 64)
  const int mrow0 = xblk * 64;
  const int k0 = ktile * 64;
  const int c4 = (t & 15) * 4;
  #pragma unroll
  for (int rep = 0; rep < 4; ++rep) {
    const int rl = (t >> 4) + 16 * rep;
    const float4 v = *(const float4*)(X + (size_t)(mrow0 + rl) * FIN + k0 + c4);
    lds[rl][c4 + 0] = v.x; lds[rl][c4 + 1] = v.y;
    lds[rl][c4 + 2] = v.z; lds[rl][c4 + 3] = v.w;
  }
  __syncthreads();
  #pragma unroll
  for (int rep = 0; rep < 2; ++rep) {
    const int s   = t + rep * 256;
    const int mt  = s >> 7;
    const int kcl = (s >> 6) & 1;
    const int ln  = s & 63;
    const int mrl = mt * 16 + (ln & 15);
    const int kb  = kcl * 32 + (ln >> 4) * 8;
    unsigned int hv[4], lv[4];
    #pragma unroll
    for (int p = 0; p < 4; ++p)
      split_pair(lds[mrl][kb + 2 * p], lds[mrl][kb + 2 * p + 1], hv[p], lv[p]);
    const size_t off = (((size_t)(xblk * 4 + mt) * 8 + (ktile * 2 + kcl)) << 9) + ln * 8;
    *(uint4*)(Xf_hi + off) = make_uint4(hv[0], hv[1], hv[2], hv[3]);
    *(uint4*)(Xf_lo + off) = make_uint4(lv[0], lv[1], lv[2], lv[3]);
  }
}

// ---- Kernel 2: [0..511] fused h=x@W (bf16x2 MFMA) + epilogue
//      [512..2559] adj rows -> EXPANDED 16-bit masks (r16: 0xFFFF/0x0000 per
//      edge, 8 MiB — gat ANDs a prefetched uint4 instead of 32 VALU/it of
//      bfe/perm bit expansion). Overlaps with gemm blocks.
__global__ __launch_bounds__(256) void gemm_fused(const unsigned short* __restrict__ Xf_hi,
                                                  const unsigned short* __restrict__ Xf_lo,
                                                  const unsigned short* __restrict__ Wf_hi,
                                                  const unsigned short* __restrict__ Wf_lo,
                                                  const float* __restrict__ adj,
                                                  const float* __restrict__ a_src,
                                                  const float* __restrict__ a_dst,
                                                  float* __restrict__ Srcv,
                                                  unsigned short* __restrict__ E1h,
                                                  unsigned short* __restrict__ E2h,
                                                  unsigned int* __restrict__ DmaxEnc,
                                                  unsigned short* __restrict__ msk,
                                                  unsigned short* __restrict__ Hf) {
  if (blockIdx.x >= 512) {
    const int row = blockIdx.x - 512;
    const int t = threadIdx.x;                 // 0..255, 8 cols each
    const float* ar = adj + (size_t)row * N + t * 8;
    const float4 v0 = *(const float4*)(ar);
    const float4 v1 = *(const float4*)(ar + 4);
    const unsigned int d0 = (v0.x != 0.f ? 0x0000FFFFu : 0u) | (v0.y != 0.f ? 0xFFFF0000u : 0u);
    const unsigned int d1 = (v0.z != 0.f ? 0x0000FFFFu : 0u) | (v0.w != 0.f ? 0xFFFF0000u : 0u);
    const unsigned int d2 = (v1.x != 0.f ? 0x0000FFFFu : 0u) | (v1.y != 0.f ? 0xFFFF0000u : 0u);
    const unsigned int d3 = (v1.z != 0.f ? 0x0000FFFFu : 0u) | (v1.w != 0.f ? 0xFFFF0000u : 0u);
    *(uint4*)(msk + (size_t)row * N + t * 8) = make_uint4(d0, d1, d2, d3);
    return;
  }
  __shared__ unsigned short sh[64][72];
  __shared__ float smax[4];
  const int xcd  = blockIdx.x & 7;
  const int slot = blockIdx.x >> 3;
  const int mb = xcd * 16 + (slot >> 2);
  const int h  = slot & 3;
  const int w = threadIdx.x >> 6, lane = threadIdx.x & 63;
  const int fl = lane & 15, quad = lane >> 4;
  const float L2E = 1.4426950408889634f;

  const float4v zero = {0.f, 0.f, 0.f, 0.f};
  float4v acc[4] = {zero, zero, zero, zero};

  const size_t abase = (((size_t)(mb * 4 + w) * 8) << 9) + lane * 8;
  #pragma unroll
  for (int kc = 0; kc < 8; ++kc) {
    const short8 Ahi = *(const short8*)(Xf_hi + abase + ((size_t)kc << 9));
    const short8 Alo = *(const short8*)(Xf_lo + abase + ((size_t)kc << 9));
    #pragma unroll
    for (int t = 0; t < 4; ++t) {
      const size_t woff = ((((size_t)h * 8 + kc) * 4 + t) << 9) + lane * 8;
      const short8 Bhi = *(const short8*)(Wf_hi + woff);
      const short8 Blo = *(const short8*)(Wf_lo + woff);
      acc[t] = __builtin_amdgcn_mfma_f32_16x16x32_bf16(Ahi, Bhi, acc[t], 0, 0, 0);
      acc[t] = __builtin_amdgcn_mfma_f32_16x16x32_bf16(Alo, Bhi, acc[t], 0, 0, 0);
      acc[t] = __builtin_amdgcn_mfma_f32_16x16x32_bf16(Ahi, Blo, acc[t], 0, 0, 0);
    }
  }

  // ---- Src dot, E-planes (f16), wave max of d ----
  const int bb  = (mb * 64) >> 11;
  const int n0w = (mb * 64) & (N - 1);
  const int bh  = bb * H + h;
  float as[4], ad[4];
  #pragma unroll
  for (int t = 0; t < 4; ++t) {
    as[t] = a_src[h * FO + t * 16 + fl];
    ad[t] = a_dst[h * FO + t * 16 + fl];
  }
  float wmax = -INFINITY;
  #pragma unroll
  for (int reg = 0; reg < 4; ++reg) {
    float sv = 0.f, dv = 0.f;
    #pragma unroll
    for (int t = 0; t < 4; ++t) {
      sv = fmaf(acc[t][reg], as[t], sv);
      dv = fmaf(acc[t][reg], ad[t], dv);
    }
    #pragma unroll
    for (int off = 1; off <= 8; off <<= 1) {
      sv += __shfl_xor(sv, off, 64);
      dv += __shfl_xor(dv, off, 64);
    }
    wmax = fmaxf(wmax, dv);
    if (fl == 0) {
      const int node = n0w + w * 16 + quad * 4 + reg;
      Srcv[(bh << 11) + node] = sv;
      const unsigned int eu = f16pk(EXP2(dv * L2E),            // exp(d)
                                    EXP2(dv * (0.2f * L2E)));  // exp(0.2 d)
      E1h[(bh << 11) + node] = (unsigned short)(eu & 0xffffu);
      E2h[(bh << 11) + node] = (unsigned short)(eu >> 16);
    }
  }
  wmax = fmaxf(wmax, __shfl_xor(wmax, 16, 64));
  wmax = fmaxf(wmax, __shfl_xor(wmax, 32, 64));
  if (lane == 0) smax[w] = wmax;

  // ---- stage f16 tile: sh[f][node] ----
  #pragma unroll
  for (int t = 0; t < 4; ++t) {
    const int nl = w * 16 + quad * 4;
    *(unsigned int*)&sh[t * 16 + fl][nl]     = f16pk(acc[t][0], acc[t][1]);
    *(unsigned int*)&sh[t * 16 + fl][nl + 2] = f16pk(acc[t][2], acc[t][3]);
  }
  __syncthreads();
  if (threadIdx.x == 0) {
    const float bmax = fmaxf(fmaxf(smax[0], smax[1]), fmaxf(smax[2], smax[3]));
    atomicMax(DmaxEnc + bh, fenc(bmax));
  }
  // ---- fragment-ordered Hf write ----
  const int jc0 = n0w >> 5;
  #pragma unroll
  for (int rep = 0; rep < 2; ++rep) {
    const int s = (int)threadIdx.x + rep * 256;
    const int jcl = s >> 8;
    const int tt  = (s >> 6) & 3;
    const int ln  = s & 63;
    const int f    = tt * 16 + (ln & 15);
    const int node = jcl * 32 + (ln >> 4) * 8;
    unsigned short* dsth = Hf + (((size_t)bh * 64 + jc0 + jcl) * 4 + tt) * 512 + ln * 8;
    *(uint4*)dsth = *(const uint4*)&sh[f][node];
  }
}

// ---- Kernel 3: MFMA flash aggregation (r16)
// Grid: B*(N/32)=256 blocks, 512 thr (8 waves: 4 heads x 2 j-halves).
// r16: (a) adjacency applied via pre-expanded 16-bit masks (1 prefetched uint4
// load + 4 ANDs per row per it, replaces 32 bfe/perm VALU ops); (b) explicit
// 2-deep ping-pong with static-named Chunk A/B + peeled tail kills the ~14
// register copies/it of the old single-buffer rotate. ~34 VALU + 10 MFMA per it.
// NOTE: plain __launch_bounds__ — min-waves bound splits unified VGPR/AGPR
// file and spills (r9: 172MB scratch traffic). Never force it.
__global__ __launch_bounds__(512) void gat_mfma(const unsigned short* __restrict__ msk,
                                                const float* __restrict__ Src,
                                                const unsigned short* __restrict__ E1h,
                                                const unsigned short* __restrict__ E2h,
                                                const unsigned int* __restrict__ DmaxEnc,
                                                const unsigned short* __restrict__ Hf,
                                                float* __restrict__ out) {
  const int xcd  = blockIdx.x & 7;
  const int slot = blockIdx.x >> 3;          // 0..31
  const int b    = xcd >> 1;
  const int i0   = ((xcd & 1) * 32 + slot) * 32;
  const int w    = threadIdx.x >> 6;         // 0..7
  const int lane = threadIdx.x & 63;
  const int h    = w & 3;
  const int jh   = w >> 2;                   // j half
  const int bh   = b * H + h;
  const int fl   = lane & 15;
  const int kk   = (lane >> 4) * 8;
  const float L2E = 1.4426950408889634f;

  const int row0 = i0 + fl;
  const int row1 = i0 + 16 + fl;
  const float dmx = fdec(DmaxEnc[bh]);
  const float s0 = Src[(bh << 11) + row0];
  const float s1 = Src[(bh << 11) + row1];
  const float u0 = s0 + dmx, m0 = fmaxf(u0, 0.2f * u0);
  const float u1 = s1 + dmx, m1 = fmaxf(u1, 0.2f * u1);
  const float c1a = EXP2((s0 - m0) * L2E), c2a = EXP2((0.2f * s0 - m0) * L2E);
  const float c1b = EXP2((s1 - m1) * L2E), c2b = EXP2((0.2f * s1 - m1) * L2E);
  // f16 row constants (all <= ~e^3.5, far inside f16 range)
  const half2v c1a2 = {(_Float16)c1a, (_Float16)c1a};
  const half2v c2a2 = {(_Float16)c2a, (_Float16)c2a};
  const half2v c1b2 = {(_Float16)c1b, (_Float16)c1b};
  const half2v c2b2 = {(_Float16)c2b, (_Float16)c2b};
  const unsigned short* mr0 = msk + (size_t)row0 * N + kk;
  const unsigned short* mr1 = msk + (size_t)row1 * N + kk;
  const unsigned short* hfb = Hf + (size_t)bh * 64 * 2048 + lane * 8;
  const unsigned short* e1b = E1h + (bh << 11);
  const unsigned short* e2b = E2h + (bh << 11);

  half8 ones;
  #pragma unroll
  for (int jj = 0; jj < 8; ++jj) ones[jj] = (_Float16)1.0f;

  const float4v zero = {0.f, 0.f, 0.f, 0.f};
  float4v acc[2][4];
  float4v accL[2];
  #pragma unroll
  for (int rt = 0; rt < 2; ++rt) {
    accL[rt] = zero;
    #pragma unroll
    for (int t = 0; t < 4; ++t) acc[rt][t] = zero;
  }

  const int jbeg = jh * (N / 2);

  auto loadc = [&](int J) -> Chunk {
    Chunk c;
    const unsigned short* hc = hfb + (size_t)(J >> 5) * 2048;
    c.b0 = *(const short8*)(hc + 0 * 512);
    c.b1 = *(const short8*)(hc + 1 * 512);
    c.b2 = *(const short8*)(hc + 2 * 512);
    c.b3 = *(const short8*)(hc + 3 * 512);
    c.e1 = *(const uint4*)(e1b + J + kk);
    c.e2 = *(const uint4*)(e2b + J + kk);
    c.m0 = *(const uint4*)(mr0 + J);
    c.m1 = *(const uint4*)(mr1 + J);
    return c;
  };

  auto compute = [&](const Chunk& c) {
    const unsigned int e1w[4] = {c.e1.x, c.e1.y, c.e1.z, c.e1.w};
    const unsigned int e2w[4] = {c.e2.x, c.e2.y, c.e2.z, c.e2.w};
    const unsigned int m0w[4] = {c.m0.x, c.m0.y, c.m0.z, c.m0.w};
    const unsigned int m1w[4] = {c.m1.x, c.m1.y, c.m1.z, c.m1.w};
    int p0i[4], p1i[4];
    #pragma unroll
    for (int p = 0; p < 4; ++p) {
      const half2v e1 = __builtin_bit_cast(half2v, e1w[p]);
      const half2v e2 = __builtin_bit_cast(half2v, e2w[p]);
      const half2v wa = __builtin_elementwise_max(c1a2 * e1, c2a2 * e2);
      const half2v wb = __builtin_elementwise_max(c1b2 * e1, c2b2 * e2);
      p0i[p] = (int)(__builtin_bit_cast(unsigned int, wa) & m0w[p]);
      p1i[p] = (int)(__builtin_bit_cast(unsigned int, wb) & m1w[p]);
    }
    const half8 p0 = __builtin_bit_cast(half8, (int4v){p0i[0], p0i[1], p0i[2], p0i[3]});
    const half8 p1 = __builtin_bit_cast(half8, (int4v){p1i[0], p1i[1], p1i[2], p1i[3]});
    const half8 hb0 = __builtin_bit_cast(half8, c.b0);
    const half8 hb1 = __builtin_bit_cast(half8, c.b1);
    const half8 hb2 = __builtin_bit_cast(half8, c.b2);
    const half8 hb3 = __builtin_bit_cast(half8, c.b3);
    acc[0][0] = __builtin_amdgcn_mfma_f32_16x16x32_f16(p0, hb0, acc[0][0], 0, 0, 0);
    acc[0][1] = __builtin_amdgcn_mfma_f32_16x16x32_f16(p0, hb1, acc[0][1], 0, 0, 0);
    acc[0][2] = __builtin_amdgcn_mfma_f32_16x16x32_f16(p0, hb2, acc[0][2], 0, 0, 0);
    acc[0][3] = __builtin_amdgcn_mfma_f32_16x16x32_f16(p0, hb3, acc[0][3], 0, 0, 0);
    accL[0]   = __builtin_amdgcn_mfma_f32_16x16x32_f16(p0, ones, accL[0], 0, 0, 0);
    acc[1][0] = __builtin_amdgcn_mfma_f32_16x16x32_f16(p1, hb0, acc[1][0], 0, 0, 0);
    acc[1][1] = __builtin_amdgcn_mfma_f32_16x16x32_f16(p1, hb1, acc[1][1], 0, 0, 0);
    acc[1][2] = __builtin_amdgcn_mfma_f32_16x16x32_f16(p1, hb2, acc[1][2], 0, 0, 0);
    acc[1][3] = __builtin_amdgcn_mfma_f32_16x16x32_f16(p1, hb3, acc[1][3], 0, 0, 0);
    accL[1]   = __builtin_amdgcn_mfma_f32_16x16x32_f16(p1, ones, accL[1], 0, 0, 0);
  };

  // ---- 2-deep ping-pong, last iteration pair peeled ----
  Chunk A = loadc(jbeg);
  for (int it = 0; it < 30; it += 2) {
    Chunk Bc = loadc(jbeg + (it + 1) * 32);
    compute(A);
    A = loadc(jbeg + (it + 2) * 32);
    compute(Bc);
  }
  {
    Chunk Bc = loadc(jbeg + 31 * 32);
    compute(A);
    compute(Bc);
  }

  // ---- combine the 2 j-halves: jh1 -> jh0 ----
  __shared__ float4v parts[4][64][11];   // 44 KiB
  if (jh == 1) {
    #pragma unroll
    for (int rt = 0; rt < 2; ++rt) {
      #pragma unroll
      for (int t = 0; t < 4; ++t) parts[h][lane][rt * 5 + t] = acc[rt][t];
      parts[h][lane][rt * 5 + 4] = accL[rt];
    }
  }
  __syncthreads();
  if (jh == 0) {
    #pragma unroll
    for (int rt = 0; rt < 2; ++rt) {
      #pragma unroll
      for (int t = 0; t < 4; ++t) acc[rt][t] += parts[h][lane][rt * 5 + t];
      accL[rt] += parts[h][lane][rt * 5 + 4];
    }
    const int quad = lane >> 4;
    #pragma unroll
    for (int rt = 0; rt < 2; ++rt) {
      #pragma unroll
      for (int reg = 0; reg < 4; ++reg) {
        const int r = i0 + rt * 16 + quad * 4 + reg;
        const float invl = 1.f / accL[rt][reg];
        float* op = out + ((size_t)(b * N) + r) * HF + h * FO + fl;
        #pragma unroll
        for (int t = 0; t < 4; ++t) op[t * 16] = acc[rt][t][reg] * invl;
      }
    }
  }
}

extern "C" void kernel_launch(void* const* d_in, const int* in_sizes, int n_in,
                              void* d_out, int out_size, void* d_ws, size_t ws_size,
                              hipStream_t stream) {
  const float* x     = (const float*)d_in[0];
  const float* adj   = (const float*)d_in[1];
  const float* W     = (const float*)d_in[2];
  const float* a_src = (const float*)d_in[3];
  const float* a_dst = (const float*)d_in[4];
  float* out = (float*)d_out;

  char* p = (char*)d_ws;
  float* Srcv = (float*)p;                  p += (size_t)B * H * N * 4;   // 128 KiB
  unsigned short* E1h = (unsigned short*)p; p += (size_t)B * H * N * 2;   // 64 KiB
  unsigned short* E2h = (unsigned short*)p; p += (size_t)B * H * N * 2;   // 64 KiB
  unsigned int* DmaxEnc = (unsigned int*)p; p += 256;
  unsigned short* Wfh = (unsigned short*)p; p += (size_t)HF * FIN * 2;    // 128 KiB
  unsigned short* Wfl = (unsigned short*)p; p += (size_t)HF * FIN * 2;    // 128 KiB
  unsigned short* Xfh = (unsigned short*)p; p += (size_t)M * FIN * 2;     // 4 MiB
  unsigned short* Xfl = (unsigned short*)p; p += (size_t)M * FIN * 2;     // 4 MiB
  unsigned short* Hf  = (unsigned short*)p; p += (size_t)M * HF * 2;      // 4 MiB
  unsigned short* msk = (unsigned short*)p;                               // 8 MiB

  prep_wx<<<dim3(528), dim3(256), 0, stream>>>(W, x, Wfh, Wfl, Xfh, Xfl, DmaxEnc);
  gemm_fused<<<dim3(512 + N), dim3(256), 0, stream>>>(Xfh, Xfl, Wfh, Wfl, adj,
                                                      a_src, a_dst,
                                                      Srcv, E1h, E2h, DmaxEnc,
                                                      msk, Hf);
  gat_mfma<<<dim3(B * (N / 32)), dim3(512), 0, stream>>>(msk,
                                                         Srcv, E1h, E2h, DmaxEnc, Hf, out);
}